// Round 12
// baseline (629.174 us; speedup 1.0000x reference)
//
#include <hip/hip_runtime.h>

// ---------------------------------------------------------------------------
// SimpleDifferentialGNN: 2x GCN encoder + global_add_pool + MLP head.
// N=100000, E=1000000, G=64, D=64, H=128, L=3
// R11: aggregate channel-pair adds via inline-asm v_pk_add_f32 (R10's f32x2
//      vector-add was scalarized by LLVM — dur identical to R8). Exact f32
//      adds, packed 2-per-instruction. Rest unchanged from R10.
// ---------------------------------------------------------------------------

#define TPB 256
#define FILL_CHUNK 2048

typedef __attribute__((ext_vector_type(8))) short bf16x8;
typedef __attribute__((ext_vector_type(8))) unsigned short u16x8;
typedef __attribute__((ext_vector_type(4))) float f32x4;
typedef __attribute__((ext_vector_type(2))) float f32x2;

__device__ __forceinline__ float bf2f(unsigned short s) {
  unsigned int u = ((unsigned int)s) << 16;
  float f;
  __builtin_memcpy(&f, &u, 4);
  return f;
}

__device__ __forceinline__ unsigned short f2bf(float f) {
  unsigned int u;
  __builtin_memcpy(&u, &f, 4);
  u = (u + 0x7FFF + ((u >> 16) & 1)) >> 16;  // RNE
  return (unsigned short)u;
}

// acc(pair) += (lo(u), hi(u)) as f32 — one v_pk_add_f32 (exact f32 adds)
__device__ __forceinline__ void pk_acc(f32x2& acc, unsigned u) {
  union { unsigned q[2]; f32x2 f; } t;
  t.q[0] = u << 16;
  t.q[1] = u & 0xffff0000u;
  asm("v_pk_add_f32 %0, %0, %1" : "+v"(acc) : "v"(t.f));
}

// ---------------- union edge counting ----------------

__global__ __launch_bounds__(TPB) void count_dst_k(const int* __restrict__ kei,
                                                   const int* __restrict__ dei,
                                                   int* __restrict__ cnt, int E) {
  int e = blockIdx.x * TPB + threadIdx.x;
  if (e >= 2 * E) return;
  int d = (e < E) ? kei[E + e] : dei[e] + 100000;
  atomicAdd(&cnt[d], 1);
}

// dinv + unified batch + graph boundaries (union: NT=2N, 128 groups)
__global__ __launch_bounds__(TPB) void prep_node_k(const int* __restrict__ cnt,
                                                   float* __restrict__ dinv,
                                                   const int* __restrict__ kb,
                                                   const int* __restrict__ db,
                                                   int* __restrict__ batchU,
                                                   int* __restrict__ gstart,
                                                   int N, int NT) {
  int i = blockIdx.x * TPB + threadIdx.x;
  if (i >= NT) return;
  dinv[i] = 1.0f / sqrtf((float)cnt[i] + 1.0f);
  int b = (i < N) ? kb[i] : db[i - N] + 64;
  batchU[i] = b;
  if (i == 0) {
    for (int g = 0; g <= b; ++g) gstart[g] = 0;
  } else {
    int pb = (i - 1 < N) ? kb[i - 1] : db[i - 1 - N] + 64;
    for (int g = pb + 1; g <= b; ++g) gstart[g] = i;
  }
  if (i == NT - 1) {
    for (int g = b + 1; g <= 128; ++g) gstart[g] = NT;
  }
}

// ---------------- multi-block exclusive scan (NT elements) ----------------

__global__ __launch_bounds__(TPB) void scan_partial_k(const int* __restrict__ cnt,
                                                      int* __restrict__ bsum, int n) {
  __shared__ int sd[TPB];
  int t = threadIdx.x, i0 = blockIdx.x * 512 + t * 2;
  int s = 0;
  if (i0 < n) s += cnt[i0];
  if (i0 + 1 < n) s += cnt[i0 + 1];
  sd[t] = s;
  __syncthreads();
  for (int st = TPB / 2; st > 0; st >>= 1) {
    if (t < st) sd[t] += sd[t + st];
    __syncthreads();
  }
  if (t == 0) bsum[blockIdx.x] = sd[0];
}

__global__ __launch_bounds__(512) void scan_small_k(const int* __restrict__ bsum,
                                                    int* __restrict__ bpre, int P,
                                                    int* __restrict__ rowptr, int n) {
  __shared__ int sd[512];
  int t = threadIdx.x;
  int v = (t < P) ? bsum[t] : 0;
  sd[t] = v;
  __syncthreads();
  for (int d = 1; d < 512; d <<= 1) {
    int w = (t >= d) ? sd[t - d] : 0;
    __syncthreads();
    sd[t] += w;
    __syncthreads();
  }
  if (t < P) bpre[t] = sd[t] - v;
  if (t == 511) rowptr[n] = sd[511];
}

__global__ __launch_bounds__(TPB) void scan_fill_k(const int* __restrict__ cnt,
                                                   const int* __restrict__ bpre,
                                                   int* __restrict__ rowptr,
                                                   int* __restrict__ cursor, int n) {
  __shared__ int sd[TPB];
  int t = threadIdx.x, i0 = blockIdx.x * 512 + t * 2;
  int c0 = (i0 < n) ? cnt[i0] : 0;
  int c1 = (i0 + 1 < n) ? cnt[i0 + 1] : 0;
  int s = c0 + c1;
  sd[t] = s;
  __syncthreads();
  for (int d = 1; d < TPB; d <<= 1) {
    int w = (t >= d) ? sd[t - d] : 0;
    __syncthreads();
    sd[t] += w;
    __syncthreads();
  }
  int ex = sd[t] - s + bpre[blockIdx.x];
  if (i0 < n) { rowptr[i0] = ex; cursor[i0] = ex; }
  if (i0 + 1 < n) { rowptr[i0 + 1] = ex + c0; cursor[i0 + 1] = ex + c0; }
}

// ---------------- CSR fill, XCD-range filtered, union edges ----------------

__global__ __launch_bounds__(TPB) void csrfill_k(const int* __restrict__ kei,
                                                 const int* __restrict__ dei,
                                                 int* __restrict__ cursor,
                                                 int* __restrict__ csr_src,
                                                 int E, int NT) {
  int range = blockIdx.x & 7;
  int chunk = blockIdx.x >> 3;
  int nper = (NT + 7) >> 3;
  int lo = range * nper;
  int hi = lo + nper; if (hi > NT) hi = NT;
  int base = chunk * FILL_CHUNK;
  int end = base + FILL_CHUNK; if (end > 2 * E) end = 2 * E;
  const int N = NT >> 1;
  for (int e = base + threadIdx.x; e < end; e += TPB) {
    int s, d;
    if (e < E) { s = kei[e]; d = kei[E + e]; }
    else       { s = dei[e - E] + N; d = dei[e] + N; }
    if (d >= lo && d < hi) {
      int p = atomicAdd(&cursor[d], 1);
      csr_src[p] = s;
    }
  }
}

// ---------------- weight prep ----------------

__global__ __launch_bounds__(TPB) void wprep_k(const float* __restrict__ encW,
                                               const float* __restrict__ convW,
                                               unsigned short* __restrict__ encWt,
                                               unsigned short* __restrict__ convWt) {
  int idx = blockIdx.x * TPB + threadIdx.x;
  if (idx < 64 * 128) {
    int k = idx >> 7, c = idx & 127;
    encWt[c * 64 + k] = f2bf(encW[idx]);
  }
  idx -= 64 * 128;
  if (idx >= 0 && idx < 3 * 128 * 128) {
    int l = idx >> 14, r = idx & 16383;
    int k = r >> 7, c = r & 127;
    convWt[l * 16384 + c * 128 + k] = f2bf(convW[idx]);
  }
}

// ---------------- MFMA GEMM ----------------

template <int K, bool BIAS, bool LNRELU, bool SCALE, bool F32IN>
__global__ __launch_bounds__(TPB) void mfma_gemm_k(
    const unsigned short* __restrict__ A, const float* __restrict__ X1,
    const float* __restrict__ X2, int nsplit,
    const unsigned short* __restrict__ Wt,
    const float* __restrict__ bias, unsigned short* __restrict__ C, int nrows,
    const int* __restrict__ batch, const float* __restrict__ meanA,
    const float* __restrict__ rsigA, const float* __restrict__ lnw,
    const float* __restrict__ lnb, const float* __restrict__ dinv) {
  __shared__ short As[128 * K];
  __shared__ short Bs[128 * K];
  const int tid = threadIdx.x;
  const int r0 = blockIdx.x << 7;
  const int lane = tid & 63;
  const int wv = tid >> 6;
  const int lr = lane & 15, lg = lane >> 4;
  constexpr int CPR = K / 8;

  for (int i = tid; i < 128 * CPR; i += TPB) {
    int rloc = i / CPR, cb = i % CPR;
    int r = r0 + rloc;
    bf16x8 v = {0, 0, 0, 0, 0, 0, 0, 0};
    if (r < nrows) {
      if (F32IN) {
        const float* Af = (r < nsplit ? X1 + (long)r * K : X2 + (long)(r - nsplit) * K) + cb * 8;
        float4 f0 = *(const float4*)Af;
        float4 f1 = *(const float4*)(Af + 4);
        v[0] = (short)f2bf(f0.x); v[1] = (short)f2bf(f0.y);
        v[2] = (short)f2bf(f0.z); v[3] = (short)f2bf(f0.w);
        v[4] = (short)f2bf(f1.x); v[5] = (short)f2bf(f1.y);
        v[6] = (short)f2bf(f1.z); v[7] = (short)f2bf(f1.w);
      } else {
        v = *(const bf16x8*)(A + (long)r * K + cb * 8);
        if (LNRELU) {
          int g = batch[r];
          float m = meanA[g], rs = rsigA[g];
          int c0 = cb * 8;
#pragma unroll
          for (int j = 0; j < 8; ++j) {
            float f = bf2f((unsigned short)v[j]);
            f = (f - m) * rs * lnw[c0 + j] + lnb[c0 + j];
            f = fmaxf(f, 0.f);
            v[j] = (short)f2bf(f);
          }
        }
      }
    }
    int sb = cb ^ (rloc & 7);
    *(bf16x8*)(&As[rloc * K + sb * 8]) = v;
  }
  for (int i = tid; i < 128 * CPR; i += TPB) {
    int rloc = i / CPR, cb = i % CPR;
    bf16x8 v = *(const bf16x8*)(Wt + (long)rloc * K + cb * 8);
    int sb = cb ^ (rloc & 7);
    *(bf16x8*)(&Bs[rloc * K + sb * 8]) = v;
  }
  __syncthreads();

  f32x4 acc[2][8];
#pragma unroll
  for (int m = 0; m < 2; ++m)
#pragma unroll
    for (int n = 0; n < 8; ++n) acc[m][n] = {0.f, 0.f, 0.f, 0.f};

  const int wrow = wv * 32;
#pragma unroll
  for (int k0 = 0; k0 < K; k0 += 32) {
    const int cbk = (k0 >> 3) + lg;
    bf16x8 a[2], b[8];
#pragma unroll
    for (int m = 0; m < 2; ++m) {
      int rr = wrow + m * 16 + lr;
      int sb = cbk ^ (rr & 7);
      a[m] = *(const bf16x8*)(&As[rr * K + sb * 8]);
    }
#pragma unroll
    for (int n = 0; n < 8; ++n) {
      int rr = n * 16 + lr;
      int sb = cbk ^ (rr & 7);
      b[n] = *(const bf16x8*)(&Bs[rr * K + sb * 8]);
    }
#pragma unroll
    for (int m = 0; m < 2; ++m)
#pragma unroll
      for (int n = 0; n < 8; ++n)
        acc[m][n] = __builtin_amdgcn_mfma_f32_16x16x32_bf16(a[m], b[n], acc[m][n], 0, 0, 0);
  }

  float bv[8];
#pragma unroll
  for (int n = 0; n < 8; ++n) bv[n] = BIAS ? bias[n * 16 + lr] : 0.f;
#pragma unroll
  for (int m = 0; m < 2; ++m) {
#pragma unroll
    for (int ri = 0; ri < 4; ++ri) {
      int r = r0 + wrow + m * 16 + lg * 4 + ri;
      if (r < nrows) {
        float dv = SCALE ? dinv[r] : 1.f;
#pragma unroll
        for (int n = 0; n < 8; ++n) {
          float v = acc[m][n][ri] + bv[n];
          if (SCALE) v *= dv;
          C[(long)r * 128 + n * 16 + lr] = f2bf(v);
        }
      }
    }
  }
}

// ---------------- aggregation (dwordx4 gather, v_pk_add_f32 accumulate) -----
// xws already dinv-scaled: out[d] = dd*(xws[d] + sum_e xws[s]) + b.
// One wave per node; 16 lanes cover one 256B row (uint4 each); 4 edge groups.
// Per dword: 2 bitops (exact bf16->f32 expand) + 1 v_pk_add_f32.

__global__ __launch_bounds__(TPB) void aggregate_k(
    const uint4* __restrict__ xws, const int* __restrict__ rowptr,
    const int* __restrict__ csr, const float* __restrict__ dinv,
    const float* __restrict__ bias, uint4* __restrict__ outb,
    float2* __restrict__ rs2, int n) {
  int wave = threadIdx.x >> 6, lane = threadIdx.x & 63;
  int d = (blockIdx.x << 2) + wave;
  if (d >= n) return;
  const int g3 = lane >> 4, cpos = lane & 15;
  f32x2 a01 = {0.f, 0.f}, a23 = {0.f, 0.f}, a45 = {0.f, 0.f}, a67 = {0.f, 0.f};

  int p0 = rowptr[d], p1 = rowptr[d + 1];
  for (int base = p0; base < p1; base += 64) {
    int idx = base + lane;
    int sl = (idx < p1) ? csr[idx] : 0;
    int cnt = p1 - base;
    if (cnt > 64) cnt = 64;
    for (int e = 0; e < cnt; e += 8) {
      int e0 = e + g3, e1 = e + 4 + g3;
      int s0 = __shfl(sl, e0);  // lanes >= cnt hold 0 -> safe row
      int s1 = __shfl(sl, e1);
      uint4 u0 = xws[(long)s0 * 16 + cpos];
      uint4 u1 = xws[(long)s1 * 16 + cpos];
      if (e0 < cnt) {
        pk_acc(a01, u0.x);
        pk_acc(a23, u0.y);
        pk_acc(a45, u0.z);
        pk_acc(a67, u0.w);
      }
      if (e1 < cnt) {
        pk_acc(a01, u1.x);
        pk_acc(a23, u1.y);
        pk_acc(a45, u1.z);
        pk_acc(a67, u1.w);
      }
    }
  }

  float acc[8] = {a01.x, a01.y, a23.x, a23.y, a45.x, a45.y, a67.x, a67.y};
#pragma unroll
  for (int j = 0; j < 8; ++j) {
    acc[j] += __shfl_xor(acc[j], 16);
    acc[j] += __shfl_xor(acc[j], 32);
  }

  uint4 su = xws[(long)d * 16 + cpos];
  float dd = dinv[d];
  float sv[8];
  sv[0] = __uint_as_float(su.x << 16);
  sv[1] = __uint_as_float(su.x & 0xffff0000u);
  sv[2] = __uint_as_float(su.y << 16);
  sv[3] = __uint_as_float(su.y & 0xffff0000u);
  sv[4] = __uint_as_float(su.z << 16);
  sv[5] = __uint_as_float(su.z & 0xffff0000u);
  sv[6] = __uint_as_float(su.w << 16);
  sv[7] = __uint_as_float(su.w & 0xffff0000u);
  const float4* b4 = (const float4*)bias;
  float4 bb0 = b4[cpos * 2];
  float4 bb1 = b4[cpos * 2 + 1];
  float val[8];
  val[0] = (acc[0] + sv[0]) * dd + bb0.x;
  val[1] = (acc[1] + sv[1]) * dd + bb0.y;
  val[2] = (acc[2] + sv[2]) * dd + bb0.z;
  val[3] = (acc[3] + sv[3]) * dd + bb0.w;
  val[4] = (acc[4] + sv[4]) * dd + bb1.x;
  val[5] = (acc[5] + sv[5]) * dd + bb1.y;
  val[6] = (acc[6] + sv[6]) * dd + bb1.z;
  val[7] = (acc[7] + sv[7]) * dd + bb1.w;

  if (g3 == 0) {
    uint4 o;
    o.x = (unsigned)f2bf(val[0]) | ((unsigned)f2bf(val[1]) << 16);
    o.y = (unsigned)f2bf(val[2]) | ((unsigned)f2bf(val[3]) << 16);
    o.z = (unsigned)f2bf(val[4]) | ((unsigned)f2bf(val[5]) << 16);
    o.w = (unsigned)f2bf(val[6]) | ((unsigned)f2bf(val[7]) << 16);
    outb[(long)d * 16 + cpos] = o;
  }

  float s1 = 0.f, s2 = 0.f;
#pragma unroll
  for (int j = 0; j < 8; ++j) {
    s1 += val[j];
    s2 += val[j] * val[j];
  }
#pragma unroll
  for (int m = 8; m >= 1; m >>= 1) {
    s1 += __shfl_xor(s1, m);
    s2 += __shfl_xor(s2, m);
  }
  if (lane == 0) rs2[d] = make_float2(s1, s2);
}

// ---------------- per-graph LN stats: 128 groups ----------------

__global__ __launch_bounds__(TPB) void gstats_k(const float2* __restrict__ rs2,
                                                const int* __restrict__ gstart,
                                                float* __restrict__ meanA,
                                                float* __restrict__ rsigA,
                                                float* __restrict__ cntA) {
  __shared__ double sd1[TPB], sd2[TPB];
  int g = blockIdx.x, t = threadIdx.x;
  int n0 = gstart[g], n1 = gstart[g + 1];
  double s1 = 0, s2 = 0;
  for (int i = n0 + t; i < n1; i += TPB) {
    float2 v = rs2[i];
    s1 += v.x; s2 += v.y;
  }
  sd1[t] = s1; sd2[t] = s2;
  __syncthreads();
  for (int st = TPB / 2; st > 0; st >>= 1) {
    if (t < st) { sd1[t] += sd1[t + st]; sd2[t] += sd2[t + st]; }
    __syncthreads();
  }
  if (t == 0) {
    double cntd = (double)(n1 - n0) * 128.0;
    if (cntd > 0.0) {
      double mean = sd1[0] / cntd;
      double var = sd2[0] / cntd - mean * mean;
      if (var < 0.0) var = 0.0;
      meanA[g] = (float)mean;
      rsigA[g] = (float)(1.0 / sqrt(var + 1e-5));
    } else {
      meanA[g] = 0.f;
      rsigA[g] = 0.f;
    }
    cntA[g] = (float)(n1 - n0);
  }
}

// ---------------- global add pool (vectorized), 128 groups ----------------

__global__ __launch_bounds__(TPB) void pool_k(const unsigned short* __restrict__ x,
                                              const int* __restrict__ gstart,
                                              float* __restrict__ part) {
  __shared__ float red[16][132];
  int g = blockIdx.x >> 3, s = blockIdx.x & 7;
  int tid = threadIdx.x;
  int ro = tid >> 4, c8 = tid & 15;
  int n0 = gstart[g], n1 = gstart[g + 1];
  float acc[8];
#pragma unroll
  for (int j = 0; j < 8; ++j) acc[j] = 0.f;
  for (int nn = n0 + s + ro * 8; nn < n1; nn += 8 * 16) {
    u16x8 v = *(const u16x8*)(x + (long)nn * 128 + c8 * 8);
#pragma unroll
    for (int j = 0; j < 8; ++j) acc[j] += bf2f(v[j]);
  }
#pragma unroll
  for (int j = 0; j < 8; ++j) red[ro][c8 * 8 + j] = acc[j];
  __syncthreads();
  for (int st = 8; st > 0; st >>= 1) {
    if (ro < st) {
#pragma unroll
      for (int j = 0; j < 8; ++j) red[ro][c8 * 8 + j] += red[ro + st][c8 * 8 + j];
    }
    __syncthreads();
  }
  if (tid < 128) part[((long)s * 128 + g) * 128 + tid] = red[0][tid];
}

// ---------------- MLP head: one block per output graph ----------------

__global__ __launch_bounds__(TPB) void head_k(
    const float* __restrict__ part, const float* __restrict__ meanU,
    const float* __restrict__ rsigU, const float* __restrict__ cntU,
    const float* __restrict__ lnw2, const float* __restrict__ lnb2,
    const float* __restrict__ W1, const float* __restrict__ b1,
    const float* __restrict__ W2, const float* __restrict__ b2,
    const float* __restrict__ W3, const float* __restrict__ b3,
    float* __restrict__ out) {
  __shared__ float ps[256];
  __shared__ float prt[256];
  __shared__ float h1[128];
  __shared__ float h2[64];
  int g = blockIdx.x, tid = threadIdx.x;
  {
    int j = tid & 127, side = tid >> 7;
    int gg = side ? 64 + g : g;
    float S = 0.f;
#pragma unroll
    for (int s = 0; s < 8; ++s) S += part[((long)s * 128 + gg) * 128 + j];
    float m = meanU[gg], r = rsigU[gg], c = cntU[gg];
    ps[tid] = lnw2[j] * r * (S - m * c) + lnb2[j] * c;
  }
  __syncthreads();
  {
    int j = tid & 127, half = tid >> 7;
    float acc = 0.f;
    const float* w = W1 + (size_t)half * 128 * 128 + j;
    const float* p = ps + half * 128;
#pragma unroll 8
    for (int k = 0; k < 128; ++k) acc = fmaf(p[k], w[(size_t)k * 128], acc);
    prt[tid] = acc;
    __syncthreads();
    if (tid < 128) h1[tid] = fmaxf(prt[tid] + prt[tid + 128] + b1[tid], 0.f);
    __syncthreads();
  }
  {
    int j = tid & 63, q = tid >> 6;
    float acc = 0.f;
    const float* w = W2 + (size_t)q * 32 * 64 + j;
    const float* p = h1 + q * 32;
#pragma unroll 8
    for (int k = 0; k < 32; ++k) acc = fmaf(p[k], w[(size_t)k * 64], acc);
    prt[tid] = acc;
    __syncthreads();
    if (tid < 64)
      h2[tid] = fmaxf(prt[tid] + prt[tid + 64] + prt[tid + 128] + prt[tid + 192] + b2[tid], 0.f);
    __syncthreads();
  }
  if (tid < 64) {
    float v = h2[tid] * W3[tid];
#pragma unroll
    for (int m = 32; m >= 1; m >>= 1) v += __shfl_xor(v, m);
    if (tid == 0) out[g] = v + b3[0];
  }
}

// ---------------------------------------------------------------------------

extern "C" void kernel_launch(void* const* d_in, const int* in_sizes, int n_in,
                              void* d_out, int out_size, void* d_ws, size_t ws_size,
                              hipStream_t stream) {
  const int N = in_sizes[2];       // 100000
  const int E = in_sizes[1] / 2;   // 1000000
  const int NT = 2 * N, ET = 2 * E;
  const int H = 128, L = 3;
  (void)n_in; (void)ws_size; (void)out_size;

  const float* kernel_x = (const float*)d_in[0];
  const int* kernel_ei  = (const int*)d_in[1];
  const int* kernel_b   = (const int*)d_in[2];
  const float* design_x = (const float*)d_in[3];
  const int* design_ei  = (const int*)d_in[4];
  const int* design_b   = (const int*)d_in[5];
  const float* encW  = (const float*)d_in[7];
  const float* encB  = (const float*)d_in[8];
  const float* convW = (const float*)d_in[9];
  const float* convB = (const float*)d_in[10];
  const float* lnw   = (const float*)d_in[11];
  const float* lnb   = (const float*)d_in[12];
  const float* W1 = (const float*)d_in[13];
  const float* b1 = (const float*)d_in[14];
  const float* W2 = (const float*)d_in[15];
  const float* b2 = (const float*)d_in[16];
  const float* W3 = (const float*)d_in[17];
  const float* b3 = (const float*)d_in[18];
  float* out = (float*)d_out;

  char* ws = (char*)d_ws;
  size_t off = 0;
  auto alloc = [&](size_t bytes) -> void* {
    void* p = ws + off;
    off = (off + bytes + 511) & ~(size_t)511;
    return p;
  };
  unsigned short* bufA = (unsigned short*)alloc((size_t)NT * H * 2);
  unsigned short* bufX = (unsigned short*)alloc((size_t)NT * H * 2);
  float* dinv    = (float*)alloc((size_t)NT * 4);
  int* cntI      = (int*)alloc((size_t)NT * 4);
  int* rowptr    = (int*)alloc((size_t)(NT + 1) * 4);
  int* cursor    = (int*)alloc((size_t)NT * 4);
  int* csr_src   = (int*)alloc((size_t)ET * 4);
  int* batchU    = (int*)alloc((size_t)NT * 4);
  int* gstart    = (int*)alloc((size_t)129 * 4);
  float2* rs2    = (float2*)alloc((size_t)NT * 8);
  float* meanS   = (float*)alloc((size_t)128 * 4);
  float* rsigS   = (float*)alloc((size_t)128 * 4);
  float* cntS    = (float*)alloc((size_t)128 * 4);
  float* meanU   = (float*)alloc((size_t)128 * 4);
  float* rsigU   = (float*)alloc((size_t)128 * 4);
  float* cntU    = (float*)alloc((size_t)128 * 4);
  float* part    = (float*)alloc((size_t)8 * 128 * 128 * 4);
  int* bsum      = (int*)alloc(512 * 4);
  int* bpre      = (int*)alloc(512 * 4);
  unsigned short* encWt  = (unsigned short*)alloc((size_t)128 * 64 * 2);
  unsigned short* convWt = (unsigned short*)alloc((size_t)L * 128 * 128 * 2);

  const int gNT   = (NT + TPB - 1) / TPB;
  const int gET   = (ET + TPB - 1) / TPB;
  const int gGemm = (NT + 127) / 128;
  const int gAgg  = (NT + 3) / 4;
  const int P     = (NT + 511) / 512;
  const int gFill = 8 * ((ET + FILL_CHUNK - 1) / FILL_CHUNK);

  wprep_k<<<(64 * 128 + 3 * 128 * 128 + TPB - 1) / TPB, TPB, 0, stream>>>(
      encW, convW, encWt, convWt);

  hipMemsetAsync(cntI, 0, (size_t)NT * 4, stream);
  count_dst_k<<<gET, TPB, 0, stream>>>(kernel_ei, design_ei, cntI, E);
  prep_node_k<<<gNT, TPB, 0, stream>>>(cntI, dinv, kernel_b, design_b, batchU,
                                       gstart, N, NT);
  scan_partial_k<<<P, TPB, 0, stream>>>(cntI, bsum, NT);
  scan_small_k<<<1, 512, 0, stream>>>(bsum, bpre, P, rowptr, NT);
  scan_fill_k<<<P, TPB, 0, stream>>>(cntI, bpre, rowptr, cursor, NT);
  csrfill_k<<<gFill, TPB, 0, stream>>>(kernel_ei, design_ei, cursor, csr_src, E, NT);

  // encoder: bufA = bf16(x @ encW + encB), both graphs
  mfma_gemm_k<64, true, false, false, true><<<gGemm, TPB, 0, stream>>>(
      nullptr, kernel_x, design_x, N, encWt, encB, bufA, NT,
      nullptr, nullptr, nullptr, nullptr, nullptr, nullptr);

  for (int i = 0; i < L; ++i) {
    float* mS = (i == L - 1) ? meanU : meanS;
    float* rS = (i == L - 1) ? rsigU : rsigS;
    float* cS = (i == L - 1) ? cntU : cntS;
    if (i == 0)
      mfma_gemm_k<128, false, false, true, false><<<gGemm, TPB, 0, stream>>>(
          bufA, nullptr, nullptr, 0, convWt + (size_t)i * H * H, nullptr, bufX, NT,
          nullptr, nullptr, nullptr, nullptr, nullptr, dinv);
    else
      mfma_gemm_k<128, false, true, true, false><<<gGemm, TPB, 0, stream>>>(
          bufA, nullptr, nullptr, 0, convWt + (size_t)i * H * H, nullptr, bufX, NT,
          batchU, meanS, rsigS, lnw + (size_t)(i - 1) * H,
          lnb + (size_t)(i - 1) * H, dinv);
    aggregate_k<<<gAgg, TPB, 0, stream>>>((const uint4*)bufX, rowptr, csr_src,
                                          dinv, convB + (size_t)i * H,
                                          (uint4*)bufA, rs2, NT);
    gstats_k<<<128, TPB, 0, stream>>>(rs2, gstart, mS, rS, cS);
  }
  pool_k<<<128 * 8, TPB, 0, stream>>>(bufA, gstart, part);

  head_k<<<64, TPB, 0, stream>>>(part, meanU, rsigU, cntU,
                                 lnw + (size_t)(L - 1) * H, lnb + (size_t)(L - 1) * H,
                                 W1, b1, W2, b2, W3, b3, out);
}

// Round 13
// 625.398 us; speedup vs baseline: 1.0060x; 1.0060x over previous
//
#include <hip/hip_runtime.h>

// ---------------------------------------------------------------------------
// SimpleDifferentialGNN: 2x GCN encoder + global_add_pool + MLP head.
// N=100000, E=1000000, G=64, D=64, H=128, L=3
// R12: aggregate 16-edge step (4 gathers in flight — R11 showed it's
//      load-depth-bound, not VALU-bound); count_dst XCD-range-filtered;
//      FILL_CHUNK 4096.
// ---------------------------------------------------------------------------

#define TPB 256
#define FILL_CHUNK 4096

typedef __attribute__((ext_vector_type(8))) short bf16x8;
typedef __attribute__((ext_vector_type(8))) unsigned short u16x8;
typedef __attribute__((ext_vector_type(4))) float f32x4;
typedef __attribute__((ext_vector_type(2))) float f32x2;

__device__ __forceinline__ float bf2f(unsigned short s) {
  unsigned int u = ((unsigned int)s) << 16;
  float f;
  __builtin_memcpy(&f, &u, 4);
  return f;
}

__device__ __forceinline__ unsigned short f2bf(float f) {
  unsigned int u;
  __builtin_memcpy(&u, &f, 4);
  u = (u + 0x7FFF + ((u >> 16) & 1)) >> 16;  // RNE
  return (unsigned short)u;
}

// acc(pair) += (lo(u), hi(u)) as f32 — one v_pk_add_f32 (exact f32 adds)
__device__ __forceinline__ void pk_acc(f32x2& acc, unsigned u) {
  union { unsigned q[2]; f32x2 f; } t;
  t.q[0] = u << 16;
  t.q[1] = u & 0xffff0000u;
  asm("v_pk_add_f32 %0, %0, %1" : "+v"(acc) : "v"(t.f));
}

// ---------------- union edge counting, XCD-range filtered ----------------
// Block b: edges in chunk (b>>3), dst in node-range (b&7) -> atomics stay in
// one XCD's L2 (no cross-XCD cnt-line bouncing).

__global__ __launch_bounds__(TPB) void count_dst_k(const int* __restrict__ kei,
                                                   const int* __restrict__ dei,
                                                   int* __restrict__ cnt,
                                                   int E, int NT) {
  int range = blockIdx.x & 7;
  int chunk = blockIdx.x >> 3;
  int nper = (NT + 7) >> 3;
  int lo = range * nper;
  int hi = lo + nper; if (hi > NT) hi = NT;
  int base = chunk * FILL_CHUNK;
  int end = base + FILL_CHUNK; if (end > 2 * E) end = 2 * E;
  const int N = NT >> 1;
  for (int e = base + threadIdx.x; e < end; e += TPB) {
    int d = (e < E) ? kei[E + e] : dei[e] + N;
    if (d >= lo && d < hi) atomicAdd(&cnt[d], 1);
  }
}

// dinv + unified batch + graph boundaries (union: NT=2N, 128 groups)
__global__ __launch_bounds__(TPB) void prep_node_k(const int* __restrict__ cnt,
                                                   float* __restrict__ dinv,
                                                   const int* __restrict__ kb,
                                                   const int* __restrict__ db,
                                                   int* __restrict__ batchU,
                                                   int* __restrict__ gstart,
                                                   int N, int NT) {
  int i = blockIdx.x * TPB + threadIdx.x;
  if (i >= NT) return;
  dinv[i] = 1.0f / sqrtf((float)cnt[i] + 1.0f);
  int b = (i < N) ? kb[i] : db[i - N] + 64;
  batchU[i] = b;
  if (i == 0) {
    for (int g = 0; g <= b; ++g) gstart[g] = 0;
  } else {
    int pb = (i - 1 < N) ? kb[i - 1] : db[i - 1 - N] + 64;
    for (int g = pb + 1; g <= b; ++g) gstart[g] = i;
  }
  if (i == NT - 1) {
    for (int g = b + 1; g <= 128; ++g) gstart[g] = NT;
  }
}

// ---------------- multi-block exclusive scan (NT elements) ----------------

__global__ __launch_bounds__(TPB) void scan_partial_k(const int* __restrict__ cnt,
                                                      int* __restrict__ bsum, int n) {
  __shared__ int sd[TPB];
  int t = threadIdx.x, i0 = blockIdx.x * 512 + t * 2;
  int s = 0;
  if (i0 < n) s += cnt[i0];
  if (i0 + 1 < n) s += cnt[i0 + 1];
  sd[t] = s;
  __syncthreads();
  for (int st = TPB / 2; st > 0; st >>= 1) {
    if (t < st) sd[t] += sd[t + st];
    __syncthreads();
  }
  if (t == 0) bsum[blockIdx.x] = sd[0];
}

__global__ __launch_bounds__(512) void scan_small_k(const int* __restrict__ bsum,
                                                    int* __restrict__ bpre, int P,
                                                    int* __restrict__ rowptr, int n) {
  __shared__ int sd[512];
  int t = threadIdx.x;
  int v = (t < P) ? bsum[t] : 0;
  sd[t] = v;
  __syncthreads();
  for (int d = 1; d < 512; d <<= 1) {
    int w = (t >= d) ? sd[t - d] : 0;
    __syncthreads();
    sd[t] += w;
    __syncthreads();
  }
  if (t < P) bpre[t] = sd[t] - v;
  if (t == 511) rowptr[n] = sd[511];
}

__global__ __launch_bounds__(TPB) void scan_fill_k(const int* __restrict__ cnt,
                                                   const int* __restrict__ bpre,
                                                   int* __restrict__ rowptr,
                                                   int* __restrict__ cursor, int n) {
  __shared__ int sd[TPB];
  int t = threadIdx.x, i0 = blockIdx.x * 512 + t * 2;
  int c0 = (i0 < n) ? cnt[i0] : 0;
  int c1 = (i0 + 1 < n) ? cnt[i0 + 1] : 0;
  int s = c0 + c1;
  sd[t] = s;
  __syncthreads();
  for (int d = 1; d < TPB; d <<= 1) {
    int w = (t >= d) ? sd[t - d] : 0;
    __syncthreads();
    sd[t] += w;
    __syncthreads();
  }
  int ex = sd[t] - s + bpre[blockIdx.x];
  if (i0 < n) { rowptr[i0] = ex; cursor[i0] = ex; }
  if (i0 + 1 < n) { rowptr[i0 + 1] = ex + c0; cursor[i0 + 1] = ex + c0; }
}

// ---------------- CSR fill, XCD-range filtered, union edges ----------------

__global__ __launch_bounds__(TPB) void csrfill_k(const int* __restrict__ kei,
                                                 const int* __restrict__ dei,
                                                 int* __restrict__ cursor,
                                                 int* __restrict__ csr_src,
                                                 int E, int NT) {
  int range = blockIdx.x & 7;
  int chunk = blockIdx.x >> 3;
  int nper = (NT + 7) >> 3;
  int lo = range * nper;
  int hi = lo + nper; if (hi > NT) hi = NT;
  int base = chunk * FILL_CHUNK;
  int end = base + FILL_CHUNK; if (end > 2 * E) end = 2 * E;
  const int N = NT >> 1;
  for (int e = base + threadIdx.x; e < end; e += TPB) {
    int s, d;
    if (e < E) { s = kei[e]; d = kei[E + e]; }
    else       { s = dei[e - E] + N; d = dei[e] + N; }
    if (d >= lo && d < hi) {
      int p = atomicAdd(&cursor[d], 1);
      csr_src[p] = s;
    }
  }
}

// ---------------- weight prep ----------------

__global__ __launch_bounds__(TPB) void wprep_k(const float* __restrict__ encW,
                                               const float* __restrict__ convW,
                                               unsigned short* __restrict__ encWt,
                                               unsigned short* __restrict__ convWt) {
  int idx = blockIdx.x * TPB + threadIdx.x;
  if (idx < 64 * 128) {
    int k = idx >> 7, c = idx & 127;
    encWt[c * 64 + k] = f2bf(encW[idx]);
  }
  idx -= 64 * 128;
  if (idx >= 0 && idx < 3 * 128 * 128) {
    int l = idx >> 14, r = idx & 16383;
    int k = r >> 7, c = r & 127;
    convWt[l * 16384 + c * 128 + k] = f2bf(convW[idx]);
  }
}

// ---------------- MFMA GEMM ----------------

template <int K, bool BIAS, bool LNRELU, bool SCALE, bool F32IN>
__global__ __launch_bounds__(TPB) void mfma_gemm_k(
    const unsigned short* __restrict__ A, const float* __restrict__ X1,
    const float* __restrict__ X2, int nsplit,
    const unsigned short* __restrict__ Wt,
    const float* __restrict__ bias, unsigned short* __restrict__ C, int nrows,
    const int* __restrict__ batch, const float* __restrict__ meanA,
    const float* __restrict__ rsigA, const float* __restrict__ lnw,
    const float* __restrict__ lnb, const float* __restrict__ dinv) {
  __shared__ short As[128 * K];
  __shared__ short Bs[128 * K];
  const int tid = threadIdx.x;
  const int r0 = blockIdx.x << 7;
  const int lane = tid & 63;
  const int wv = tid >> 6;
  const int lr = lane & 15, lg = lane >> 4;
  constexpr int CPR = K / 8;

  for (int i = tid; i < 128 * CPR; i += TPB) {
    int rloc = i / CPR, cb = i % CPR;
    int r = r0 + rloc;
    bf16x8 v = {0, 0, 0, 0, 0, 0, 0, 0};
    if (r < nrows) {
      if (F32IN) {
        const float* Af = (r < nsplit ? X1 + (long)r * K : X2 + (long)(r - nsplit) * K) + cb * 8;
        float4 f0 = *(const float4*)Af;
        float4 f1 = *(const float4*)(Af + 4);
        v[0] = (short)f2bf(f0.x); v[1] = (short)f2bf(f0.y);
        v[2] = (short)f2bf(f0.z); v[3] = (short)f2bf(f0.w);
        v[4] = (short)f2bf(f1.x); v[5] = (short)f2bf(f1.y);
        v[6] = (short)f2bf(f1.z); v[7] = (short)f2bf(f1.w);
      } else {
        v = *(const bf16x8*)(A + (long)r * K + cb * 8);
        if (LNRELU) {
          int g = batch[r];
          float m = meanA[g], rs = rsigA[g];
          int c0 = cb * 8;
#pragma unroll
          for (int j = 0; j < 8; ++j) {
            float f = bf2f((unsigned short)v[j]);
            f = (f - m) * rs * lnw[c0 + j] + lnb[c0 + j];
            f = fmaxf(f, 0.f);
            v[j] = (short)f2bf(f);
          }
        }
      }
    }
    int sb = cb ^ (rloc & 7);
    *(bf16x8*)(&As[rloc * K + sb * 8]) = v;
  }
  for (int i = tid; i < 128 * CPR; i += TPB) {
    int rloc = i / CPR, cb = i % CPR;
    bf16x8 v = *(const bf16x8*)(Wt + (long)rloc * K + cb * 8);
    int sb = cb ^ (rloc & 7);
    *(bf16x8*)(&Bs[rloc * K + sb * 8]) = v;
  }
  __syncthreads();

  f32x4 acc[2][8];
#pragma unroll
  for (int m = 0; m < 2; ++m)
#pragma unroll
    for (int n = 0; n < 8; ++n) acc[m][n] = {0.f, 0.f, 0.f, 0.f};

  const int wrow = wv * 32;
#pragma unroll
  for (int k0 = 0; k0 < K; k0 += 32) {
    const int cbk = (k0 >> 3) + lg;
    bf16x8 a[2], b[8];
#pragma unroll
    for (int m = 0; m < 2; ++m) {
      int rr = wrow + m * 16 + lr;
      int sb = cbk ^ (rr & 7);
      a[m] = *(const bf16x8*)(&As[rr * K + sb * 8]);
    }
#pragma unroll
    for (int n = 0; n < 8; ++n) {
      int rr = n * 16 + lr;
      int sb = cbk ^ (rr & 7);
      b[n] = *(const bf16x8*)(&Bs[rr * K + sb * 8]);
    }
#pragma unroll
    for (int m = 0; m < 2; ++m)
#pragma unroll
      for (int n = 0; n < 8; ++n)
        acc[m][n] = __builtin_amdgcn_mfma_f32_16x16x32_bf16(a[m], b[n], acc[m][n], 0, 0, 0);
  }

  float bv[8];
#pragma unroll
  for (int n = 0; n < 8; ++n) bv[n] = BIAS ? bias[n * 16 + lr] : 0.f;
#pragma unroll
  for (int m = 0; m < 2; ++m) {
#pragma unroll
    for (int ri = 0; ri < 4; ++ri) {
      int r = r0 + wrow + m * 16 + lg * 4 + ri;
      if (r < nrows) {
        float dv = SCALE ? dinv[r] : 1.f;
#pragma unroll
        for (int n = 0; n < 8; ++n) {
          float v = acc[m][n][ri] + bv[n];
          if (SCALE) v *= dv;
          C[(long)r * 128 + n * 16 + lr] = f2bf(v);
        }
      }
    }
  }
}

// ---------------- aggregation (16-edge step: 4 gathers in flight) ----------
// xws already dinv-scaled: out[d] = dd*(xws[d] + sum_e xws[s]) + b.
// One wave per node; 16 lanes cover one 256B row (uint4 each); 4 edge groups;
// 4 independent row-gathers issued back-to-back per iteration (deep MLP).

__global__ __launch_bounds__(TPB) void aggregate_k(
    const uint4* __restrict__ xws, const int* __restrict__ rowptr,
    const int* __restrict__ csr, const float* __restrict__ dinv,
    const float* __restrict__ bias, uint4* __restrict__ outb,
    float2* __restrict__ rs2, int n) {
  int wave = threadIdx.x >> 6, lane = threadIdx.x & 63;
  int d = (blockIdx.x << 2) + wave;
  if (d >= n) return;
  const int g3 = lane >> 4, cpos = lane & 15;
  f32x2 a01 = {0.f, 0.f}, a23 = {0.f, 0.f}, a45 = {0.f, 0.f}, a67 = {0.f, 0.f};

#define ACCQ(U)      \
  {                  \
    pk_acc(a01, (U).x); \
    pk_acc(a23, (U).y); \
    pk_acc(a45, (U).z); \
    pk_acc(a67, (U).w); \
  }

  int p0 = rowptr[d], p1 = rowptr[d + 1];
  for (int base = p0; base < p1; base += 64) {
    int idx = base + lane;
    int sl = (idx < p1) ? csr[idx] : 0;
    int cnt = p1 - base;
    if (cnt > 64) cnt = 64;
    for (int e = 0; e < cnt; e += 16) {
      int e0 = e + g3, e1 = e + 4 + g3, e2 = e + 8 + g3, e3 = e + 12 + g3;
      int s0 = __shfl(sl, e0);  // lanes >= cnt hold 0 -> safe row
      int s1 = __shfl(sl, e1);
      int s2 = __shfl(sl, e2);
      int s3 = __shfl(sl, e3);
      uint4 u0 = xws[(long)s0 * 16 + cpos];
      uint4 u1 = xws[(long)s1 * 16 + cpos];
      uint4 u2 = xws[(long)s2 * 16 + cpos];
      uint4 u3 = xws[(long)s3 * 16 + cpos];
      if (e0 < cnt) ACCQ(u0);
      if (e1 < cnt) ACCQ(u1);
      if (e2 < cnt) ACCQ(u2);
      if (e3 < cnt) ACCQ(u3);
    }
  }
#undef ACCQ

  float acc[8] = {a01.x, a01.y, a23.x, a23.y, a45.x, a45.y, a67.x, a67.y};
#pragma unroll
  for (int j = 0; j < 8; ++j) {
    acc[j] += __shfl_xor(acc[j], 16);
    acc[j] += __shfl_xor(acc[j], 32);
  }

  uint4 su = xws[(long)d * 16 + cpos];
  float dd = dinv[d];
  float sv[8];
  sv[0] = __uint_as_float(su.x << 16);
  sv[1] = __uint_as_float(su.x & 0xffff0000u);
  sv[2] = __uint_as_float(su.y << 16);
  sv[3] = __uint_as_float(su.y & 0xffff0000u);
  sv[4] = __uint_as_float(su.z << 16);
  sv[5] = __uint_as_float(su.z & 0xffff0000u);
  sv[6] = __uint_as_float(su.w << 16);
  sv[7] = __uint_as_float(su.w & 0xffff0000u);
  const float4* b4 = (const float4*)bias;
  float4 bb0 = b4[cpos * 2];
  float4 bb1 = b4[cpos * 2 + 1];
  float val[8];
  val[0] = (acc[0] + sv[0]) * dd + bb0.x;
  val[1] = (acc[1] + sv[1]) * dd + bb0.y;
  val[2] = (acc[2] + sv[2]) * dd + bb0.z;
  val[3] = (acc[3] + sv[3]) * dd + bb0.w;
  val[4] = (acc[4] + sv[4]) * dd + bb1.x;
  val[5] = (acc[5] + sv[5]) * dd + bb1.y;
  val[6] = (acc[6] + sv[6]) * dd + bb1.z;
  val[7] = (acc[7] + sv[7]) * dd + bb1.w;

  if (g3 == 0) {
    uint4 o;
    o.x = (unsigned)f2bf(val[0]) | ((unsigned)f2bf(val[1]) << 16);
    o.y = (unsigned)f2bf(val[2]) | ((unsigned)f2bf(val[3]) << 16);
    o.z = (unsigned)f2bf(val[4]) | ((unsigned)f2bf(val[5]) << 16);
    o.w = (unsigned)f2bf(val[6]) | ((unsigned)f2bf(val[7]) << 16);
    outb[(long)d * 16 + cpos] = o;
  }

  float s1 = 0.f, s2 = 0.f;
#pragma unroll
  for (int j = 0; j < 8; ++j) {
    s1 += val[j];
    s2 += val[j] * val[j];
  }
#pragma unroll
  for (int m = 8; m >= 1; m >>= 1) {
    s1 += __shfl_xor(s1, m);
    s2 += __shfl_xor(s2, m);
  }
  if (lane == 0) rs2[d] = make_float2(s1, s2);
}

// ---------------- per-graph LN stats: 128 groups ----------------

__global__ __launch_bounds__(TPB) void gstats_k(const float2* __restrict__ rs2,
                                                const int* __restrict__ gstart,
                                                float* __restrict__ meanA,
                                                float* __restrict__ rsigA,
                                                float* __restrict__ cntA) {
  __shared__ double sd1[TPB], sd2[TPB];
  int g = blockIdx.x, t = threadIdx.x;
  int n0 = gstart[g], n1 = gstart[g + 1];
  double s1 = 0, s2 = 0;
  for (int i = n0 + t; i < n1; i += TPB) {
    float2 v = rs2[i];
    s1 += v.x; s2 += v.y;
  }
  sd1[t] = s1; sd2[t] = s2;
  __syncthreads();
  for (int st = TPB / 2; st > 0; st >>= 1) {
    if (t < st) { sd1[t] += sd1[t + st]; sd2[t] += sd2[t + st]; }
    __syncthreads();
  }
  if (t == 0) {
    double cntd = (double)(n1 - n0) * 128.0;
    if (cntd > 0.0) {
      double mean = sd1[0] / cntd;
      double var = sd2[0] / cntd - mean * mean;
      if (var < 0.0) var = 0.0;
      meanA[g] = (float)mean;
      rsigA[g] = (float)(1.0 / sqrt(var + 1e-5));
    } else {
      meanA[g] = 0.f;
      rsigA[g] = 0.f;
    }
    cntA[g] = (float)(n1 - n0);
  }
}

// ---------------- global add pool (vectorized), 128 groups ----------------

__global__ __launch_bounds__(TPB) void pool_k(const unsigned short* __restrict__ x,
                                              const int* __restrict__ gstart,
                                              float* __restrict__ part) {
  __shared__ float red[16][132];
  int g = blockIdx.x >> 3, s = blockIdx.x & 7;
  int tid = threadIdx.x;
  int ro = tid >> 4, c8 = tid & 15;
  int n0 = gstart[g], n1 = gstart[g + 1];
  float acc[8];
#pragma unroll
  for (int j = 0; j < 8; ++j) acc[j] = 0.f;
  for (int nn = n0 + s + ro * 8; nn < n1; nn += 8 * 16) {
    u16x8 v = *(const u16x8*)(x + (long)nn * 128 + c8 * 8);
#pragma unroll
    for (int j = 0; j < 8; ++j) acc[j] += bf2f(v[j]);
  }
#pragma unroll
  for (int j = 0; j < 8; ++j) red[ro][c8 * 8 + j] = acc[j];
  __syncthreads();
  for (int st = 8; st > 0; st >>= 1) {
    if (ro < st) {
#pragma unroll
      for (int j = 0; j < 8; ++j) red[ro][c8 * 8 + j] += red[ro + st][c8 * 8 + j];
    }
    __syncthreads();
  }
  if (tid < 128) part[((long)s * 128 + g) * 128 + tid] = red[0][tid];
}

// ---------------- MLP head: one block per output graph ----------------

__global__ __launch_bounds__(TPB) void head_k(
    const float* __restrict__ part, const float* __restrict__ meanU,
    const float* __restrict__ rsigU, const float* __restrict__ cntU,
    const float* __restrict__ lnw2, const float* __restrict__ lnb2,
    const float* __restrict__ W1, const float* __restrict__ b1,
    const float* __restrict__ W2, const float* __restrict__ b2,
    const float* __restrict__ W3, const float* __restrict__ b3,
    float* __restrict__ out) {
  __shared__ float ps[256];
  __shared__ float prt[256];
  __shared__ float h1[128];
  __shared__ float h2[64];
  int g = blockIdx.x, tid = threadIdx.x;
  {
    int j = tid & 127, side = tid >> 7;
    int gg = side ? 64 + g : g;
    float S = 0.f;
#pragma unroll
    for (int s = 0; s < 8; ++s) S += part[((long)s * 128 + gg) * 128 + j];
    float m = meanU[gg], r = rsigU[gg], c = cntU[gg];
    ps[tid] = lnw2[j] * r * (S - m * c) + lnb2[j] * c;
  }
  __syncthreads();
  {
    int j = tid & 127, half = tid >> 7;
    float acc = 0.f;
    const float* w = W1 + (size_t)half * 128 * 128 + j;
    const float* p = ps + half * 128;
#pragma unroll 8
    for (int k = 0; k < 128; ++k) acc = fmaf(p[k], w[(size_t)k * 128], acc);
    prt[tid] = acc;
    __syncthreads();
    if (tid < 128) h1[tid] = fmaxf(prt[tid] + prt[tid + 128] + b1[tid], 0.f);
    __syncthreads();
  }
  {
    int j = tid & 63, q = tid >> 6;
    float acc = 0.f;
    const float* w = W2 + (size_t)q * 32 * 64 + j;
    const float* p = h1 + q * 32;
#pragma unroll 8
    for (int k = 0; k < 32; ++k) acc = fmaf(p[k], w[(size_t)k * 64], acc);
    prt[tid] = acc;
    __syncthreads();
    if (tid < 64)
      h2[tid] = fmaxf(prt[tid] + prt[tid + 64] + prt[tid + 128] + prt[tid + 192] + b2[tid], 0.f);
    __syncthreads();
  }
  if (tid < 64) {
    float v = h2[tid] * W3[tid];
#pragma unroll
    for (int m = 32; m >= 1; m >>= 1) v += __shfl_xor(v, m);
    if (tid == 0) out[g] = v + b3[0];
  }
}

// ---------------------------------------------------------------------------

extern "C" void kernel_launch(void* const* d_in, const int* in_sizes, int n_in,
                              void* d_out, int out_size, void* d_ws, size_t ws_size,
                              hipStream_t stream) {
  const int N = in_sizes[2];       // 100000
  const int E = in_sizes[1] / 2;   // 1000000
  const int NT = 2 * N, ET = 2 * E;
  const int H = 128, L = 3;
  (void)n_in; (void)ws_size; (void)out_size;

  const float* kernel_x = (const float*)d_in[0];
  const int* kernel_ei  = (const int*)d_in[1];
  const int* kernel_b   = (const int*)d_in[2];
  const float* design_x = (const float*)d_in[3];
  const int* design_ei  = (const int*)d_in[4];
  const int* design_b   = (const int*)d_in[5];
  const float* encW  = (const float*)d_in[7];
  const float* encB  = (const float*)d_in[8];
  const float* convW = (const float*)d_in[9];
  const float* convB = (const float*)d_in[10];
  const float* lnw   = (const float*)d_in[11];
  const float* lnb   = (const float*)d_in[12];
  const float* W1 = (const float*)d_in[13];
  const float* b1 = (const float*)d_in[14];
  const float* W2 = (const float*)d_in[15];
  const float* b2 = (const float*)d_in[16];
  const float* W3 = (const float*)d_in[17];
  const float* b3 = (const float*)d_in[18];
  float* out = (float*)d_out;

  char* ws = (char*)d_ws;
  size_t off = 0;
  auto alloc = [&](size_t bytes) -> void* {
    void* p = ws + off;
    off = (off + bytes + 511) & ~(size_t)511;
    return p;
  };
  unsigned short* bufA = (unsigned short*)alloc((size_t)NT * H * 2);
  unsigned short* bufX = (unsigned short*)alloc((size_t)NT * H * 2);
  float* dinv    = (float*)alloc((size_t)NT * 4);
  int* cntI      = (int*)alloc((size_t)NT * 4);
  int* rowptr    = (int*)alloc((size_t)(NT + 1) * 4);
  int* cursor    = (int*)alloc((size_t)NT * 4);
  int* csr_src   = (int*)alloc((size_t)ET * 4);
  int* batchU    = (int*)alloc((size_t)NT * 4);
  int* gstart    = (int*)alloc((size_t)129 * 4);
  float2* rs2    = (float2*)alloc((size_t)NT * 8);
  float* meanS   = (float*)alloc((size_t)128 * 4);
  float* rsigS   = (float*)alloc((size_t)128 * 4);
  float* cntS    = (float*)alloc((size_t)128 * 4);
  float* meanU   = (float*)alloc((size_t)128 * 4);
  float* rsigU   = (float*)alloc((size_t)128 * 4);
  float* cntU    = (float*)alloc((size_t)128 * 4);
  float* part    = (float*)alloc((size_t)8 * 128 * 128 * 4);
  int* bsum      = (int*)alloc(512 * 4);
  int* bpre      = (int*)alloc(512 * 4);
  unsigned short* encWt  = (unsigned short*)alloc((size_t)128 * 64 * 2);
  unsigned short* convWt = (unsigned short*)alloc((size_t)L * 128 * 128 * 2);

  const int gNT   = (NT + TPB - 1) / TPB;
  const int gGemm = (NT + 127) / 128;
  const int gAgg  = (NT + 3) / 4;
  const int P     = (NT + 511) / 512;
  const int gFill = 8 * ((ET + FILL_CHUNK - 1) / FILL_CHUNK);

  wprep_k<<<(64 * 128 + 3 * 128 * 128 + TPB - 1) / TPB, TPB, 0, stream>>>(
      encW, convW, encWt, convWt);

  hipMemsetAsync(cntI, 0, (size_t)NT * 4, stream);
  count_dst_k<<<gFill, TPB, 0, stream>>>(kernel_ei, design_ei, cntI, E, NT);
  prep_node_k<<<gNT, TPB, 0, stream>>>(cntI, dinv, kernel_b, design_b, batchU,
                                       gstart, N, NT);
  scan_partial_k<<<P, TPB, 0, stream>>>(cntI, bsum, NT);
  scan_small_k<<<1, 512, 0, stream>>>(bsum, bpre, P, rowptr, NT);
  scan_fill_k<<<P, TPB, 0, stream>>>(cntI, bpre, rowptr, cursor, NT);
  csrfill_k<<<gFill, TPB, 0, stream>>>(kernel_ei, design_ei, cursor, csr_src, E, NT);

  // encoder: bufA = bf16(x @ encW + encB), both graphs
  mfma_gemm_k<64, true, false, false, true><<<gGemm, TPB, 0, stream>>>(
      nullptr, kernel_x, design_x, N, encWt, encB, bufA, NT,
      nullptr, nullptr, nullptr, nullptr, nullptr, nullptr);

  for (int i = 0; i < L; ++i) {
    float* mS = (i == L - 1) ? meanU : meanS;
    float* rS = (i == L - 1) ? rsigU : rsigS;
    float* cS = (i == L - 1) ? cntU : cntS;
    if (i == 0)
      mfma_gemm_k<128, false, false, true, false><<<gGemm, TPB, 0, stream>>>(
          bufA, nullptr, nullptr, 0, convWt + (size_t)i * H * H, nullptr, bufX, NT,
          nullptr, nullptr, nullptr, nullptr, nullptr, dinv);
    else
      mfma_gemm_k<128, false, true, true, false><<<gGemm, TPB, 0, stream>>>(
          bufA, nullptr, nullptr, 0, convWt + (size_t)i * H * H, nullptr, bufX, NT,
          batchU, meanS, rsigS, lnw + (size_t)(i - 1) * H,
          lnb + (size_t)(i - 1) * H, dinv);
    aggregate_k<<<gAgg, TPB, 0, stream>>>((const uint4*)bufX, rowptr, csr_src,
                                          dinv, convB + (size_t)i * H,
                                          (uint4*)bufA, rs2, NT);
    gstats_k<<<128, TPB, 0, stream>>>(rs2, gstart, mS, rS, cS);
  }
  pool_k<<<128 * 8, TPB, 0, stream>>>(bufA, gstart, part);

  head_k<<<64, TPB, 0, stream>>>(part, meanU, rsigU, cntU,
                                 lnw + (size_t)(L - 1) * H, lnb + (size_t)(L - 1) * H,
                                 W1, b1, W2, b2, W3, b3, out);
}